// Round 1
// baseline (481.799 us; speedup 1.0000x reference)
//
#include <hip/hip_runtime.h>

#define NN 4096
#define FF 256
#define EE 65536
#define MAXDEG 128
#define MAXEPR 512
#define NCAND 2048

// ---------------------------------------------------------------------------
// K1: scatter edges into dense A; build per-row edge-id lists
// ---------------------------------------------------------------------------
__global__ void k_scatter(const int* __restrict__ ei, const float* __restrict__ ew,
                          float* __restrict__ A, int* __restrict__ ecnt,
                          int* __restrict__ elist) {
    int e = blockIdx.x * blockDim.x + threadIdx.x;
    if (e >= EE) return;
    int r = ei[e];
    int c = ei[EE + e];
    float w = ew[e];
    atomicAdd(&A[(size_t)r * NN + c], w);
    int p = atomicAdd(&ecnt[r], 1);
    if (p < MAXEPR) elist[r * MAXEPR + p] = e;
}

// ---------------------------------------------------------------------------
// K2: finalize A (clamp>1 -> 1, zero diag) and build CSR (one wave per row)
// ---------------------------------------------------------------------------
__global__ void k_csr(float* __restrict__ A, unsigned short* __restrict__ ccol,
                      float* __restrict__ cval, int* __restrict__ deg) {
    int wave = threadIdx.x >> 6;
    int lane = threadIdx.x & 63;
    int row = blockIdx.x * (blockDim.x >> 6) + wave;
    if (row >= NN) return;
    size_t base = (size_t)row * NN;
    int cnt = 0;
    for (int b = 0; b < NN; b += 64) {
        int c = b + lane;
        float v = A[base + c];
        v = (c == row) ? 0.f : fminf(v, 1.f);
        A[base + c] = v;
        unsigned long long m = __ballot(v != 0.f);
        int pos = cnt + __popcll(m & ((1ull << lane) - 1ull));
        if (v != 0.f && pos < MAXDEG) {
            ccol[row * MAXDEG + pos] = (unsigned short)c;
            cval[row * MAXDEG + pos] = v;
        }
        cnt += __popcll(m);
    }
    if (lane == 0) deg[row] = cnt;
}

// ---------------------------------------------------------------------------
// K3: sq[i] = sum_j X[i][j]^2 in f64 (one wave per row, 4 f32/lane)
// ---------------------------------------------------------------------------
__global__ void k_sq(const float* __restrict__ X, double* __restrict__ sq) {
    int wave = threadIdx.x >> 6;
    int lane = threadIdx.x & 63;
    int row = blockIdx.x * (blockDim.x >> 6) + wave;
    if (row >= NN) return;
    float4 x4 = ((const float4*)(X + (size_t)row * FF))[lane];
    double s = (double)x4.x * x4.x + (double)x4.y * x4.y +
               (double)x4.z * x4.z + (double)x4.w * x4.w;
#pragma unroll
    for (int o = 32; o >= 1; o >>= 1) s += __shfl_xor(s, o);
    if (lane == 0) sq[row] = s;
}

// ---------------------------------------------------------------------------
// K4: d_thres = mean(deg) + 2*std(deg), single block
// ---------------------------------------------------------------------------
__global__ void k_stats(const int* __restrict__ deg, double* __restrict__ thres) {
    __shared__ double sd[256], sd2[256];
    int t = threadIdx.x;
    double s = 0, s2 = 0;
    for (int i = t; i < NN; i += 256) {
        double d = (double)deg[i];
        s += d; s2 += d * d;
    }
    sd[t] = s; sd2[t] = s2;
    __syncthreads();
    for (int o = 128; o >= 1; o >>= 1) {
        if (t < o) { sd[t] += sd[t + o]; sd2[t] += sd2[t + o]; }
        __syncthreads();
    }
    if (t == 0) {
        double mean = sd[0] / NN;
        double var = sd2[0] / NN - mean * mean;
        if (var < 0) var = 0;
        thres[0] = mean + 2.0 * sqrt(var);
    }
}

// ---------------------------------------------------------------------------
// K5: per-row main kernel. Builds A^2 row in LDS, candidate list, distances,
//     then per-edge rank test and output.
// ---------------------------------------------------------------------------
__launch_bounds__(256, 1)
__global__ void k_main(const int* __restrict__ ei, const float* __restrict__ ew,
                       const float* __restrict__ X, const float* __restrict__ th1p,
                       const float* __restrict__ th2p, const float* __restrict__ A,
                       const unsigned short* __restrict__ ccol,
                       const float* __restrict__ cval, const int* __restrict__ deg,
                       const int* __restrict__ ecnt, const int* __restrict__ elist,
                       const double* __restrict__ sq, const double* __restrict__ thresp,
                       float* __restrict__ out) {
    __shared__ float acc[NN];            // A2 row values
    __shared__ float ddist[NN];          // dense dist lookup (set for candidates)
    __shared__ float Xu[FF];
    __shared__ unsigned short cidx[NCAND];
    __shared__ float cdist[NCAND];
    __shared__ int ncand;

    const int u = blockIdx.x;
    const int tid = threadIdx.x;
    const int lane = tid & 63;
    const int wave = tid >> 6;

    for (int i = tid; i < NN; i += 256) acc[i] = 0.f;
    if (tid < FF / 4)
        ((float4*)Xu)[tid] = ((const float4*)(X + (size_t)u * FF))[tid];
    __syncthreads();

    // --- build A2 row: A' = A(final) + I; acc[v] += A'[u][k]*A'[k][v] ---
    const int du = deg[u];
    const int dul = min(du, MAXDEG);
    for (int kk = wave; kk <= dul; kk += 4) {
        int k; float wuk;
        if (kk == dul) { k = u; wuk = 1.f; }           // self term A'[u][u]=1
        else { k = ccol[u * MAXDEG + kk]; wuk = cval[u * MAXDEG + kk]; }
        int dkl = min(deg[k], MAXDEG);
        for (int j = lane; j <= dkl; j += 64) {
            int v; float wkv;
            if (j == dkl) { v = k; wkv = 1.f; }        // self term A'[k][k]=1
            else { v = ccol[k * MAXDEG + j]; wkv = cval[k * MAXDEG + j]; }
            atomicAdd(&acc[v], wuk * wkv);
        }
    }
    __syncthreads();
    if (tid == 0) { acc[u] = 0.f; ncand = 0; }         // zero diag of A2
    __syncthreads();

    // --- compact 2-hop candidates ---
    for (int i = tid; i < NN; i += 256) {
        if (acc[i] != 0.f) {
            int p = atomicAdd(&ncand, 1);
            if (p < NCAND) cidx[p] = (unsigned short)i;
        }
    }
    __syncthreads();
    const int Dr = ncand;
    const int Drs = min(Dr, NCAND);

    // --- distances: one candidate per wave, f64 dot, rounded to f32 ---
    const double squ = sq[u];
    for (int c = wave; c < Drs; c += 4) {
        int v = cidx[c];
        float4 xv = ((const float4*)(X + (size_t)v * FF))[lane];
        float4 xu = ((const float4*)Xu)[lane];
        double s = (double)xv.x * xu.x + (double)xv.y * xu.y +
                   (double)xv.z * xu.z + (double)xv.w * xu.w;
#pragma unroll
        for (int o = 32; o >= 1; o >>= 1) s += __shfl_xor(s, o);
        if (lane == 0) {
            float dv = (float)(squ + sq[v] - 2.0 * s);
            cdist[c] = dv;
            ddist[v] = dv;
        }
    }
    __syncthreads();

    // --- per-edge output ---
    const int D = du;
    const bool highD = ((double)D > thresp[0]);
    const int nz = Dr - 2 * D;                         // nz_sel
    const float th1 = th1p[0], th2 = th2p[0];
    int ne = ecnt[u]; if (ne > MAXEPR) ne = MAXEPR;
    for (int idx = tid; idx < ne; idx += 256) {
        int e = elist[u * MAXEPR + idx];
        int v = ei[EE + e];
        float w = ew[e];
        float a2v = acc[v];
        float av = A[(size_t)u * NN + v];
        float adj;
        if (highD) {
            adj = (av != 0.f) ? (a2v - av) : 0.f;      // Z_high = (A==0)
        } else if (nz < 0) {
            adj = a2v - av;                             // nosparse: Z = false
        } else if (nz == 0) {
            adj = 0.f;                                  // nz_eff=N: all nbrs masked; non-nbrs A2-A=0
        } else if (a2v == 0.f) {
            adj = 0.f;                                  // not a 2-hop nbr: A2-A = 0 (A subset A2)
        } else {
            // stable descending rank of v among candidates
            float dv = ddist[v];
            int cnt = 0;
            for (int c = 0; c < Drs; ++c) {
                float cd = cdist[c];
                int ci = cidx[c];
                cnt += (cd > dv || (cd == dv && ci < v)) ? 1 : 0;
            }
            adj = (cnt < nz) ? 0.f : (a2v - av);
        }
        out[e] = fmaxf(0.f, fmaf(th1, w, th2 * adj));
    }
}

// ---------------------------------------------------------------------------
extern "C" void kernel_launch(void* const* d_in, const int* in_sizes, int n_in,
                              void* d_out, int out_size, void* d_ws, size_t ws_size,
                              hipStream_t stream) {
    const int* ei = (const int*)d_in[0];
    const float* ew = (const float*)d_in[1];
    const float* X = (const float*)d_in[2];
    const float* th1 = (const float*)d_in[3];
    const float* th2 = (const float*)d_in[4];
    float* out = (float*)d_out;

    char* ws = (char*)d_ws;
    size_t off = 0;
    float* A = (float*)(ws + off);            off += (size_t)NN * NN * 4;    // 64MB
    unsigned short* ccol = (unsigned short*)(ws + off); off += (size_t)NN * MAXDEG * 2;
    float* cval = (float*)(ws + off);         off += (size_t)NN * MAXDEG * 4;
    int* deg = (int*)(ws + off);              off += (size_t)NN * 4;
    int* elist = (int*)(ws + off);            off += (size_t)NN * MAXEPR * 4;
    int* ecnt = (int*)(ws + off);             off += (size_t)NN * 4;
    double* sq = (double*)(ws + off);         off += (size_t)NN * 8;
    double* thres = (double*)(ws + off);      off += 256;

    hipMemsetAsync(A, 0, (size_t)NN * NN * 4, stream);
    hipMemsetAsync(ecnt, 0, (size_t)NN * 4, stream);

    k_scatter<<<EE / 256, 256, 0, stream>>>(ei, ew, A, ecnt, elist);
    k_csr<<<NN / 4, 256, 0, stream>>>(A, ccol, cval, deg);
    k_sq<<<NN / 4, 256, 0, stream>>>(X, sq);
    k_stats<<<1, 256, 0, stream>>>(deg, thres);
    k_main<<<NN, 256, 0, stream>>>(ei, ew, X, th1, th2, A, ccol, cval, deg,
                                   ecnt, elist, sq, thres, out);
}

// Round 2
// 308.151 us; speedup vs baseline: 1.5635x; 1.5635x over previous
//
#include <hip/hip_runtime.h>

#define NN 4096
#define FF 256
#define EE 65536
#define MAXDEG 128
#define MAXEPR 512
#define NCAND 2048

__device__ __forceinline__ float wred_max(float v) {
#pragma unroll
    for (int o = 32; o >= 1; o >>= 1) v = fmaxf(v, __shfl_xor(v, o));
    return v;
}
__device__ __forceinline__ int wred_sum(int v) {
#pragma unroll
    for (int o = 32; o >= 1; o >>= 1) v += __shfl_xor(v, o);
    return v;
}

// ---------------------------------------------------------------------------
// K1: scatter edges into dense A; build per-row edge-id lists
// ---------------------------------------------------------------------------
__global__ void k_scatter(const int* __restrict__ ei, const float* __restrict__ ew,
                          float* __restrict__ A, int* __restrict__ ecnt,
                          int* __restrict__ elist) {
    int e = blockIdx.x * blockDim.x + threadIdx.x;
    if (e >= EE) return;
    int r = ei[e];
    int c = ei[EE + e];
    float w = ew[e];
    atomicAdd(&A[(size_t)r * NN + c], w);
    int p = atomicAdd(&ecnt[r], 1);
    if (p < MAXEPR) elist[r * MAXEPR + p] = e;
}

// ---------------------------------------------------------------------------
// K2: finalize A (clamp>1 -> 1, zero diag) and build CSR (one wave per row).
// CSR column order is irrelevant (consumed via atomic accumulation only), so
// we compact with 4 independent ballots per float4 chunk.
// ---------------------------------------------------------------------------
__global__ void k_csr(float* __restrict__ A, unsigned short* __restrict__ ccol,
                      float* __restrict__ cval, int* __restrict__ deg) {
    int wave = threadIdx.x >> 6;
    int lane = threadIdx.x & 63;
    int row = blockIdx.x * (blockDim.x >> 6) + wave;
    if (row >= NN) return;
    size_t base = (size_t)row * NN;
    unsigned long long lmask = (1ull << lane) - 1ull;
    int cnt = 0;
    for (int b = 0; b < NN; b += 256) {
        int c0 = b + lane * 4;
        float4 v = ((float4*)(A + base))[b / 4 + lane];
        v.x = (c0 + 0 == row) ? 0.f : fminf(v.x, 1.f);
        v.y = (c0 + 1 == row) ? 0.f : fminf(v.y, 1.f);
        v.z = (c0 + 2 == row) ? 0.f : fminf(v.z, 1.f);
        v.w = (c0 + 3 == row) ? 0.f : fminf(v.w, 1.f);
        ((float4*)(A + base))[b / 4 + lane] = v;
        float e[4] = {v.x, v.y, v.z, v.w};
#pragma unroll
        for (int j = 0; j < 4; ++j) {
            unsigned long long m = __ballot(e[j] != 0.f);
            int pos = cnt + __popcll(m & lmask);
            if (e[j] != 0.f && pos < MAXDEG) {
                ccol[row * MAXDEG + pos] = (unsigned short)(c0 + j);
                cval[row * MAXDEG + pos] = e[j];
            }
            cnt += __popcll(m);
        }
    }
    if (lane == 0) deg[row] = cnt;
}

// ---------------------------------------------------------------------------
// K3: sq[i] = sum_j X[i][j]^2 in f64 (one wave per row, 4 f32/lane)
// ---------------------------------------------------------------------------
__global__ void k_sq(const float* __restrict__ X, double* __restrict__ sq) {
    int wave = threadIdx.x >> 6;
    int lane = threadIdx.x & 63;
    int row = blockIdx.x * (blockDim.x >> 6) + wave;
    if (row >= NN) return;
    float4 x4 = ((const float4*)(X + (size_t)row * FF))[lane];
    double s = (double)x4.x * x4.x + (double)x4.y * x4.y +
               (double)x4.z * x4.z + (double)x4.w * x4.w;
#pragma unroll
    for (int o = 32; o >= 1; o >>= 1) s += __shfl_xor(s, o);
    if (lane == 0) sq[row] = s;
}

// ---------------------------------------------------------------------------
// K4: d_thres = mean(deg) + 2*std(deg), single block
// ---------------------------------------------------------------------------
__global__ void k_stats(const int* __restrict__ deg, double* __restrict__ thres) {
    __shared__ double sd[256], sd2[256];
    int t = threadIdx.x;
    double s = 0, s2 = 0;
    for (int i = t; i < NN; i += 256) {
        double d = (double)deg[i];
        s += d; s2 += d * d;
    }
    sd[t] = s; sd2[t] = s2;
    __syncthreads();
    for (int o = 128; o >= 1; o >>= 1) {
        if (t < o) { sd[t] += sd[t + o]; sd2[t] += sd2[t + o]; }
        __syncthreads();
    }
    if (t == 0) {
        double mean = sd[0] / NN;
        double var = sd2[0] / NN - mean * mean;
        if (var < 0) var = 0;
        thres[0] = mean + 2.0 * sqrt(var);
    }
}

// ---------------------------------------------------------------------------
// K5: per-row main kernel.
// ---------------------------------------------------------------------------
__launch_bounds__(256, 5)
__global__ void k_main(const int* __restrict__ ei, const float* __restrict__ ew,
                       const float* __restrict__ X, const float* __restrict__ th1p,
                       const float* __restrict__ th2p, const float* __restrict__ A,
                       const unsigned short* __restrict__ ccol,
                       const float* __restrict__ cval, const int* __restrict__ deg,
                       const int* __restrict__ ecnt, const int* __restrict__ elist,
                       const double* __restrict__ sq, const double* __restrict__ thresp,
                       float* __restrict__ out) {
    __shared__ float acc[NN];            // A2 row values (16KB)
    __shared__ float Xu[FF];             // 1KB
    __shared__ unsigned short cidx[NCAND]; // 4KB
    __shared__ float cdist[NCAND];       // 8KB
    __shared__ int ncand;

    const int u = blockIdx.x;
    const int tid = threadIdx.x;
    const int lane = tid & 63;
    const int wave = tid >> 6;
    const unsigned long long lmask = (1ull << lane) - 1ull;

    for (int i = tid; i < NN; i += 256) acc[i] = 0.f;
    if (tid < FF / 4)
        ((float4*)Xu)[tid] = ((const float4*)(X + (size_t)u * FF))[tid];
    if (tid == 0) ncand = 0;
    __syncthreads();

    // --- build A2 row: A' = A(final) + I; acc[v] += A'[u][k]*A'[k][v] ---
    const int du = deg[u];
    const int dul = min(du, MAXDEG);
    for (int kk = wave; kk <= dul; kk += 4) {
        int k; float wuk;
        if (kk == dul) { k = u; wuk = 1.f; }           // self term A'[u][u]=1
        else { k = ccol[u * MAXDEG + kk]; wuk = cval[u * MAXDEG + kk]; }
        int dkl = min(deg[k], MAXDEG);
        for (int j = lane; j <= dkl; j += 64) {
            int v; float wkv;
            if (j == dkl) { v = k; wkv = 1.f; }        // self term A'[k][k]=1
            else { v = ccol[k * MAXDEG + j]; wkv = cval[k * MAXDEG + j]; }
            atomicAdd(&acc[v], wuk * wkv);
        }
    }
    __syncthreads();
    if (tid == 0) acc[u] = 0.f;                        // zero diag of A2
    __syncthreads();

    // --- compact 2-hop candidates (ballot-aggregated, order irrelevant) ---
    for (int i = tid; i < NN; i += 256) {
        bool nz = (acc[i] != 0.f);
        unsigned long long m = __ballot(nz);
        int base = 0;
        if (lane == 0 && m) base = atomicAdd(&ncand, __popcll(m));
        base = __shfl(base, 0);
        int pos = base + __popcll(m & lmask);
        if (nz && pos < NCAND) cidx[pos] = (unsigned short)i;
    }
    __syncthreads();
    const int Dr = ncand;
    const int Drs = min(Dr, NCAND);

    // --- distances: one candidate per THREAD, f64 accumulate, round to f32 ---
    const double squ = sq[u];
    for (int c = tid; c < Drs; c += 256) {
        int v = cidx[c];
        const float4* Xv = (const float4*)(X + (size_t)v * FF);
        double s0 = 0.0, s1 = 0.0;
#pragma unroll 4
        for (int f = 0; f < FF / 4; f += 2) {
            float4 a = Xv[f];
            float4 b = ((const float4*)Xu)[f];
            s0 += (double)a.x * b.x + (double)a.y * b.y +
                  (double)a.z * b.z + (double)a.w * b.w;
            float4 p = Xv[f + 1];
            float4 q = ((const float4*)Xu)[f + 1];
            s1 += (double)p.x * q.x + (double)p.y * q.y +
                  (double)p.z * q.z + (double)p.w * q.w;
        }
        cdist[c] = (float)(squ + sq[v] - 2.0 * (s0 + s1));
    }
    __syncthreads();

    // --- per-edge output: one WAVE per edge, lane-parallel rank scan ---
    const int D = du;
    const bool highD = ((double)D > thresp[0]);
    const int nz = Dr - 2 * D;                         // nz_sel
    const float th1 = th1p[0], th2 = th2p[0];
    int ne = ecnt[u]; if (ne > MAXEPR) ne = MAXEPR;
    for (int idx = wave; idx < ne; idx += 4) {
        int e = elist[u * MAXEPR + idx];
        int v = ei[EE + e];                            // wave-uniform
        float w = ew[e];
        float a2v = acc[v];
        float av = A[(size_t)u * NN + v];
        float adj;
        if (highD) {
            adj = (av != 0.f) ? (a2v - av) : 0.f;      // Z_high = (A==0)
        } else if (nz < 0) {
            adj = a2v - av;                             // nosparse: Z = false
        } else if (nz == 0) {
            adj = 0.f;                                  // all nbrs masked
        } else if (a2v == 0.f) {
            adj = 0.f;                                  // not a 2-hop nbr
        } else {
            // find dv, then stable descending rank of v among candidates
            float dvl = -3.4e38f;
            for (int c = lane; c < Drs; c += 64)
                if ((int)cidx[c] == v) dvl = cdist[c];
            float dv = wred_max(dvl);
            int cnt = 0;
            for (int c = lane; c < Drs; c += 64) {
                float cd = cdist[c];
                int ci = cidx[c];
                cnt += (cd > dv || (cd == dv && ci < v)) ? 1 : 0;
            }
            cnt = wred_sum(cnt);
            adj = (cnt < nz) ? 0.f : (a2v - av);
        }
        if (lane == 0) out[e] = fmaxf(0.f, fmaf(th1, w, th2 * adj));
    }
}

// ---------------------------------------------------------------------------
extern "C" void kernel_launch(void* const* d_in, const int* in_sizes, int n_in,
                              void* d_out, int out_size, void* d_ws, size_t ws_size,
                              hipStream_t stream) {
    const int* ei = (const int*)d_in[0];
    const float* ew = (const float*)d_in[1];
    const float* X = (const float*)d_in[2];
    const float* th1 = (const float*)d_in[3];
    const float* th2 = (const float*)d_in[4];
    float* out = (float*)d_out;

    char* ws = (char*)d_ws;
    size_t off = 0;
    float* A = (float*)(ws + off);            off += (size_t)NN * NN * 4;    // 64MB
    unsigned short* ccol = (unsigned short*)(ws + off); off += (size_t)NN * MAXDEG * 2;
    float* cval = (float*)(ws + off);         off += (size_t)NN * MAXDEG * 4;
    int* deg = (int*)(ws + off);              off += (size_t)NN * 4;
    int* elist = (int*)(ws + off);            off += (size_t)NN * MAXEPR * 4;
    int* ecnt = (int*)(ws + off);             off += (size_t)NN * 4;
    double* sq = (double*)(ws + off);         off += (size_t)NN * 8;
    double* thres = (double*)(ws + off);      off += 256;

    hipMemsetAsync(A, 0, (size_t)NN * NN * 4, stream);
    hipMemsetAsync(ecnt, 0, (size_t)NN * 4, stream);

    k_scatter<<<EE / 256, 256, 0, stream>>>(ei, ew, A, ecnt, elist);
    k_csr<<<NN / 4, 256, 0, stream>>>(A, ccol, cval, deg);
    k_sq<<<NN / 4, 256, 0, stream>>>(X, sq);
    k_stats<<<1, 256, 0, stream>>>(deg, thres);
    k_main<<<NN, 256, 0, stream>>>(ei, ew, X, th1, th2, A, ccol, cval, deg,
                                   ecnt, elist, sq, thres, out);
}